// Round 9
// baseline (557.209 us; speedup 1.0000x reference)
//
#include <hip/hip_runtime.h>
#include <hip/hip_cooperative_groups.h>
#include <hip/hip_bf16.h>
#include <math.h>

namespace cg = cooperative_groups;

#define N_NODES 10000
#define N_EDGES 160000
#define DIN 128
#define DW 512
#define NHEAD 8
#define NC 64
#define MPAD 10112     // 79 * 128
#define GEMM_BLKS 316  // 79 * 4
#define NBLK 512
#define NTHR 512

typedef unsigned short ushort_t;
typedef __attribute__((ext_vector_type(8))) short bf16x8;
typedef __attribute__((ext_vector_type(8))) unsigned short us8;
typedef __attribute__((ext_vector_type(4))) float f32x4;

__device__ inline ushort_t f2bf(float v) {
    unsigned u = __builtin_bit_cast(unsigned, v);
    return (ushort_t)((u + 0x7fff + ((u >> 16) & 1)) >> 16);
}
__device__ inline float bf2f(ushort_t h) {
    return __builtin_bit_cast(float, (unsigned)h << 16);
}

// swizzled tile-major index: tiles of 128 rows x 64 k, 8192 ushort each.
__device__ __forceinline__ size_t swz_idx(int rb, int r, int kp, int nkt) {
    int kt = kp >> 6, kc = kp & 63;
    return ((size_t)(rb * nkt + kt)) * 8192 + r * 64 + (kc ^ ((r & 7) << 3));
}

__device__ __forceinline__ void gld16(const ushort_t* g, ushort_t* l) {
    __builtin_amdgcn_global_load_lds(
        (const __attribute__((address_space(1))) void*)g,
        (__attribute__((address_space(3))) void*)l, 16, 0, 0);
}

// ================= shared-memory union for the mega kernel =================
union SMem {
    struct { ushort_t A[2][8192]; ushort_t B[2][8192]; } g;                     // 64 KB
    struct { int ps[512]; float red[16]; ushort_t st[1024]; } ln;               // ~4.2 KB
    struct { float wls[64][NHEAD]; int sls[64]; float aDn[NHEAD];
             float dsum[NHEAD]; float part[256][2]; } ag;                       // ~4.4 KB
    struct { float Ws[8192]; float gl[32][16]; float a2[32]; } g2;              // ~34.3 KB
};

struct MegaArgs {
    const float *x, *ftW, *ftb, *lng, *lnb, *W1, *as1, *ad1, *b1,
                *bng, *bnb, *bnm, *bnv, *W2, *as2, *ad2, *b2;
    const int* ei;
    float* out;
    ushort_t *Ax, *Bx, *B1, *h0big, *h1b, *h2b;
    float *hpre, *gbuf, *aS, *aD;
    int *cnt, *cursor, *off, *csrc;
};

// ================= GEMM phase body (identical schedule to round 8) =================
template<int KT, bool ATT>
__device__ __forceinline__ void gemm_phase(SMem& sm,
    const ushort_t* __restrict__ A, const ushort_t* __restrict__ Bm,
    float* __restrict__ C, ushort_t* __restrict__ Cb,
    const float* __restrict__ asrc, const float* __restrict__ adst,
    float* __restrict__ aS, float* __restrict__ aD, int bid, int t)
{
    int bx = bid >> 2, by = bid & 3;
    int w = t >> 6, l = t & 63;
    int lm = l & 15, g = l >> 4;
    int wr = w >> 1, wc = w & 1;
    int rowbase = bx * 128;
    int colbase = by * 128;

    const ushort_t* Abase = A + (size_t)bx * KT * 8192 + t * 8;
    const ushort_t* Bbase = Bm + (size_t)by * KT * 8192 + t * 8;

    f32x4 acc[2][4];
    #pragma unroll
    for (int r = 0; r < 2; r++)
        #pragma unroll
        for (int c = 0; c < 4; c++) acc[r][c] = (f32x4){0.f, 0.f, 0.f, 0.f};

    #pragma unroll
    for (int j = 0; j < 2; ++j) {
        gld16(Abase + j * 4096, &sm.g.A[0][j * 4096 + t * 8]);
        gld16(Bbase + j * 4096, &sm.g.B[0][j * 4096 + t * 8]);
    }

    int p = 0;
    for (int kt = 0; kt < KT; ++kt) {
        __builtin_amdgcn_s_barrier();
        if (kt + 1 < KT) {
            const ushort_t* ga = Abase + (size_t)(kt + 1) * 8192;
            const ushort_t* gb = Bbase + (size_t)(kt + 1) * 8192;
            #pragma unroll
            for (int j = 0; j < 2; ++j) {
                gld16(ga + j * 4096, &sm.g.A[p ^ 1][j * 4096 + t * 8]);
                gld16(gb + j * 4096, &sm.g.B[p ^ 1][j * 4096 + t * 8]);
            }
            asm volatile("s_waitcnt vmcnt(4)" ::: "memory");
        } else {
            asm volatile("s_waitcnt vmcnt(0)" ::: "memory");
        }
        __builtin_amdgcn_s_barrier();
        const char* Ap = (const char*)sm.g.A[p];
        const char* Bp = (const char*)sm.g.B[p];
        #pragma unroll
        for (int ks = 0; ks < 2; ++ks) {
            bf16x8 af[2], bfr[4];
            #pragma unroll
            for (int r = 0; r < 2; ++r) {
                int row = wr * 32 + r * 16 + lm;
                af[r] = *(const bf16x8*)(Ap + row * 128 +
                                         ((ks * 64 + g * 16) ^ ((row & 7) << 4)));
            }
            #pragma unroll
            for (int c = 0; c < 4; ++c) {
                int col = wc * 64 + c * 16 + lm;
                bfr[c] = *(const bf16x8*)(Bp + col * 128 +
                                          ((ks * 64 + g * 16) ^ ((col & 7) << 4)));
            }
            #pragma unroll
            for (int r = 0; r < 2; ++r)
                #pragma unroll
                for (int c = 0; c < 4; ++c)
                    acc[r][c] = __builtin_amdgcn_mfma_f32_16x16x32_bf16(af[r], bfr[c], acc[r][c], 0, 0, 0);
        }
        p ^= 1;
    }

    if (!ATT) {
        #pragma unroll
        for (int r = 0; r < 2; ++r) {
            int row0 = rowbase + wr * 32 + r * 16 + g * 4;
            #pragma unroll
            for (int c = 0; c < 4; ++c) {
                int col = colbase + wc * 64 + c * 16 + lm;
                #pragma unroll
                for (int q = 0; q < 4; ++q)
                    if (row0 + q < N_NODES) C[(size_t)(row0 + q) * DW + col] = acc[r][c][q];
            }
        }
    } else {
        int h = 2 * by + wc;
        float asv[4], adv[4];
        #pragma unroll
        for (int c = 0; c < 4; ++c) {
            asv[c] = asrc[h * NC + c * 16 + lm];
            adv[c] = adst[h * NC + c * 16 + lm];
        }
        #pragma unroll
        for (int r = 0; r < 2; ++r) {
            int row0 = rowbase + wr * 32 + r * 16 + g * 4;
            #pragma unroll
            for (int c = 0; c < 4; ++c) {
                int col = colbase + wc * 64 + c * 16 + lm;
                #pragma unroll
                for (int q = 0; q < 4; ++q)
                    if (row0 + q < N_NODES) Cb[(size_t)(row0 + q) * DW + col] = f2bf(acc[r][c][q]);
            }
            #pragma unroll
            for (int q = 0; q < 4; ++q) {
                float ss = acc[r][0][q] * asv[0] + acc[r][1][q] * asv[1] +
                           acc[r][2][q] * asv[2] + acc[r][3][q] * asv[3];
                float dd = acc[r][0][q] * adv[0] + acc[r][1][q] * adv[1] +
                           acc[r][2][q] * adv[2] + acc[r][3][q] * adv[3];
                #pragma unroll
                for (int m = 1; m < 16; m <<= 1) {
                    ss += __shfl_xor(ss, m, 64);
                    dd += __shfl_xor(dd, m, 64);
                }
                int row = row0 + q;
                if (lm == 0 && row < N_NODES) {
                    aS[row * NHEAD + h] = ss;
                    aD[row * NHEAD + h] = dd;
                }
            }
        }
    }
}

// ================= the cooperative mega kernel =================
__global__ __launch_bounds__(NTHR, 4) void k_mega(MegaArgs a) {
    cg::grid_group grid = cg::this_grid();
    __shared__ __align__(16) SMem sm;
    int bid = blockIdx.x, t = threadIdx.x;
    int gtid = bid * NTHR + t;

    // ---- P0: prep Ax/Bx/B1 + zero cnt/cursor ----
    for (int u = gtid; u < 499472; u += NBLK * NTHR) {
        if (u < 161792) {                    // Ax[MPAD][256] = [xhi | xlo], 16B chunks
            int n = u >> 4, k0 = (u & 15) * 8;
            float v[8];
            if (n < N_NODES) {
                #pragma unroll
                for (int q = 0; q < 8; q++) v[q] = a.x[n * DIN + k0 + q];
            } else {
                #pragma unroll
                for (int q = 0; q < 8; q++) v[q] = 0.f;
            }
            us8 hi, lo;
            #pragma unroll
            for (int q = 0; q < 8; q++) {
                ushort_t h = f2bf(v[q]); hi[q] = h; lo[q] = f2bf(v[q] - bf2f(h));
            }
            int rb = n >> 7, r = n & 127;
            *(us8*)(a.Ax + swz_idx(rb, r, k0, 4)) = hi;
            *(us8*)(a.Ax + swz_idx(rb, r, 128 + k0, 4)) = lo;
        } else if (u < 227328) {             // Bx[512][256] = [Whi | Whi]
            int i = u - 161792;
            int n = i >> 7, k = i & 127;
            ushort_t h = f2bf(a.ftW[k * DW + n]);
            int cb = n >> 7, rc = n & 127;
            a.Bx[swz_idx(cb, rc, k, 4)] = h;
            a.Bx[swz_idx(cb, rc, 128 + k, 4)] = h;
        } else if (u < 489472) {             // B1[512][1024] = [W1hi | W1hi]
            int i = u - 227328;
            int n = i >> 9, k = i & 511;
            ushort_t h = f2bf(a.W1[k * DW + n]);
            int cb = n >> 7, rc = n & 127;
            a.B1[swz_idx(cb, rc, k, 16)] = h;
            a.B1[swz_idx(cb, rc, 512 + k, 16)] = h;
        } else {                             // zero
            int i = u - 489472;
            a.cnt[i] = 0; a.cursor[i] = 0;
        }
    }
    grid.sync();

    // ---- P1: ft GEMM (K'=256) || CSR count ----
    if (bid < GEMM_BLKS) {
        gemm_phase<4, false>(sm, a.Ax, a.Bx, a.hpre, nullptr, nullptr, nullptr,
                             nullptr, nullptr, bid, t);
    } else {
        for (int e = (bid - GEMM_BLKS) * NTHR + t; e < N_EDGES; e += (NBLK - GEMM_BLKS) * NTHR)
            atomicAdd(&a.cnt[a.ei[N_EDGES + e]], 1);
    }
    grid.sync();

    // ---- P2: LN -> h0big [hi|lo] || CSR scan (block 0) ----
    if (bid == 0) {
        int base = t * 20;
        int loc[20]; int s = 0;
        #pragma unroll
        for (int i = 0; i < 20; i++) {
            int idx = base + i;
            int v = idx < N_NODES ? a.cnt[idx] : 0;
            loc[i] = s; s += v;
        }
        sm.ln.ps[t] = s; __syncthreads();
        for (int o = 1; o < 512; o <<= 1) {
            int v = (t >= o) ? sm.ln.ps[t - o] : 0;
            __syncthreads();
            sm.ln.ps[t] += v;
            __syncthreads();
        }
        int pre = t ? sm.ln.ps[t - 1] : 0;
        #pragma unroll
        for (int i = 0; i < 20; i++) {
            int idx = base + i;
            if (idx < N_NODES) a.off[idx] = pre + loc[i];
        }
        if (t == 511) a.off[N_NODES] = sm.ln.ps[511];
    } else {
        for (int n = bid - 1; n < MPAD; n += NBLK - 1) {
            int rb = n >> 7, r = n & 127;
            if (n >= N_NODES) {
                if (t < 128) {
                    int kp0 = t * 8;
                    *(us8*)(a.h0big + swz_idx(rb, r, kp0, 16)) = (us8){0,0,0,0,0,0,0,0};
                }
                continue;
            }
            float av = a.hpre[(size_t)n * DW + t] + a.ftb[t];
            float s = av, sq = av * av;
            for (int o = 32; o > 0; o >>= 1) { s += __shfl_down(s, o, 64); sq += __shfl_down(sq, o, 64); }
            int wid = t >> 6;
            if ((t & 63) == 0) { sm.ln.red[wid] = s; sm.ln.red[8 + wid] = sq; }
            __syncthreads();
            if (t == 0) {
                float ts = 0.f, tq = 0.f;
                #pragma unroll
                for (int q = 0; q < 8; q++) { ts += sm.ln.red[q]; tq += sm.ln.red[8 + q]; }
                float mu = ts / DW;
                float var = tq / DW - mu * mu;
                sm.ln.red[0] = mu; sm.ln.red[1] = rsqrtf(var + 1e-5f);
            }
            __syncthreads();
            float mu = sm.ln.red[0], rs = sm.ln.red[1];
            float v = (av - mu) * rs * a.lng[t] + a.lnb[t];
            v = v >= 0.f ? v : 0.2f * v;
            ushort_t h = f2bf(v);
            sm.ln.st[t] = h;
            sm.ln.st[512 + t] = f2bf(v - bf2f(h));
            __syncthreads();
            if (t < 128) {
                int kp0 = t * 8;
                *(us8*)(a.h0big + swz_idx(rb, r, kp0, 16)) = *(const us8*)(sm.ln.st + kp0);
            }
            __syncthreads();
        }
    }
    grid.sync();

    // ---- P3: GEMM1 (K'=1024) + fused att-dots || CSR scatter ----
    if (bid < GEMM_BLKS) {
        gemm_phase<16, true>(sm, a.h0big, a.B1, nullptr, a.h1b, a.as1, a.ad1,
                             a.aS, a.aD, bid, t);
    } else {
        for (int e = (bid - GEMM_BLKS) * NTHR + t; e < N_EDGES; e += (NBLK - GEMM_BLKS) * NTHR) {
            int d = a.ei[N_EDGES + e];
            int p = a.off[d] + atomicAdd(&a.cursor[d], 1);
            a.csrc[p] = a.ei[e];
        }
    }
    grid.sync();

    // ---- P4: layer-1 aggregation (softmax + bias + BN + ReLU -> bf16 h2) ----
    {
        int th = t & 255, half = t >> 8;
        int hA = th >> 5;
        int j0 = 2 * th, j1 = j0 + 1;
        float b10 = a.b1[j0], b11 = a.b1[j1];
        float sc0 = rsqrtf(a.bnv[j0] + 1e-5f) * a.bng[j0];
        float sc1 = rsqrtf(a.bnv[j1] + 1e-5f) * a.bng[j1];
        float mn0 = a.bnm[j0], mn1 = a.bnm[j1];
        float bb0 = a.bnb[j0], bb1 = a.bnb[j1];
        for (int n = bid; n < N_NODES; n += NBLK) {
            int beg = a.off[n], end = a.off[n + 1];
            if (t < NHEAD) { sm.ag.aDn[t] = a.aD[n * NHEAD + t]; sm.ag.dsum[t] = 0.f; }
            __syncthreads();
            float acc0 = 0.f, acc1 = 0.f, dpart = 0.f;
            for (int c = beg; c < end; c += 64) {
                int m = min(64, end - c);
                if (t < m) sm.ag.sls[t] = a.csrc[c + t];
                __syncthreads();
                for (int idx = t; idx < m * NHEAD; idx += NTHR) {
                    int el = idx >> 3, h = idx & 7;
                    float l = a.aS[sm.ag.sls[el] * NHEAD + h] + sm.ag.aDn[h];
                    l = l >= 0.f ? l : 0.2f * l;
                    float w = __expf(l);
                    sm.ag.wls[el][h] = w;
                    dpart += w;
                }
                __syncthreads();
                for (int el = half; el < m; el += 2) {
                    float w = sm.ag.wls[el][hA];
                    unsigned v = *(const unsigned*)(a.h1b + (size_t)sm.ag.sls[el] * DW + j0);
                    acc0 += w * __builtin_bit_cast(float, v << 16);
                    acc1 += w * __builtin_bit_cast(float, v & 0xffff0000u);
                }
                __syncthreads();
            }
            if (half) { sm.ag.part[th][0] = acc0; sm.ag.part[th][1] = acc1; }
            for (int o = 8; o < 64; o <<= 1) dpart += __shfl_down(dpart, o, 64);
            if ((t & 63) < NHEAD) atomicAdd(&sm.ag.dsum[t & 7], dpart);
            __syncthreads();
            if (!half) {
                acc0 += sm.ag.part[th][0];
                acc1 += sm.ag.part[th][1];
                float rd = sm.ag.dsum[hA] > 0.f ? 1.f / sm.ag.dsum[hA] : 0.f;
                float v0 = (acc0 * rd + b10 - mn0) * sc0 + bb0;
                v0 = v0 > 0.f ? v0 : 0.f;
                float v1 = (acc1 * rd + b11 - mn1) * sc1 + bb1;
                v1 = v1 > 0.f ? v1 : 0.f;
                unsigned pk = (unsigned)f2bf(v0) | ((unsigned)f2bf(v1) << 16);
                *(unsigned*)(a.h2b + (size_t)n * DW + j0) = pk;
            }
            __syncthreads();
        }
    }
    grid.sync();

    // ---- P5: GEMM2 + fused att2 (32 nodes / block) ----
    {
        for (int i = t; i < 8192; i += NTHR) sm.g2.Ws[i] = a.W2[i];
        if (t < 16) sm.g2.a2[t] = a.as2[t];
        else if (t < 32) sm.g2.a2[t] = a.ad2[t - 16];
        __syncthreads();
        int g0 = bid * 32;
        if (g0 < N_NODES) {
            int nl = t >> 4, j = t & 15;
            int node = g0 + nl;
            float acc = 0.f;
            if (node < N_NODES) {
                const bf16x8* hr = (const bf16x8*)(a.h2b + (size_t)node * DW);
                for (int ks = 0; ks < DW / 8; ks++) {
                    bf16x8 v = hr[ks];
                    #pragma unroll
                    for (int q = 0; q < 8; q++)
                        acc += bf2f((ushort_t)v[q]) * sm.g2.Ws[(ks * 8 + q) * 16 + j];
                }
                a.gbuf[node * 16 + j] = acc;
            }
            sm.g2.gl[nl][j] = acc;
            __syncthreads();
            if (node < N_NODES) {
                if (j < 8) {
                    a.aS[node * NHEAD + j] =
                        sm.g2.gl[nl][2 * j] * sm.g2.a2[2 * j] +
                        sm.g2.gl[nl][2 * j + 1] * sm.g2.a2[2 * j + 1];
                } else {
                    int h = j - 8;
                    a.aD[node * NHEAD + h] =
                        sm.g2.gl[nl][2 * h] * sm.g2.a2[16 + 2 * h] +
                        sm.g2.gl[nl][2 * h + 1] * sm.g2.a2[16 + 2 * h + 1];
                }
            }
        }
    }
    grid.sync();

    // ---- P6: layer-2 aggregation + head-mean + b2 -> out ----
    {
        int lane = t & 63;
        int j = lane & 15, slot = lane >> 4, h = j >> 1;
        for (int n = bid * 8 + (t >> 6); n < N_NODES; n += NBLK * 8) {
            int beg = a.off[n], end = a.off[n + 1];
            float adn = a.aD[n * NHEAD + h];
            float acc = 0.f, den = 0.f;
            for (int c = beg + slot; c < end; c += 4) {
                int s = a.csrc[c];
                float l = a.aS[s * NHEAD + h] + adn;
                l = l >= 0.f ? l : 0.2f * l;
                float w = __expf(l);
                den += w;
                acc += w * a.gbuf[s * 16 + j];
            }
            acc += __shfl_down(acc, 16, 64); acc += __shfl_down(acc, 32, 64);
            den += __shfl_down(den, 16, 64); den += __shfl_down(den, 32, 64);
            float v = (lane < 16 && den > 0.f) ? acc / den : 0.f;
            v += __shfl_down(v, 2, 64);
            v += __shfl_down(v, 4, 64);
            v += __shfl_down(v, 8, 64);
            if (lane < 2) a.out[n * 2 + lane] = v * 0.125f + a.b2[lane];
        }
    }
}

// ====================================================================
// ================= FALLBACK: round-8 7-kernel path ==================
// ====================================================================
__global__ void k_prep(const float* __restrict__ x, const float* __restrict__ ftW,
                       const float* __restrict__ W1f,
                       ushort_t* __restrict__ Ax, ushort_t* __restrict__ Bx,
                       ushort_t* __restrict__ B1,
                       int* __restrict__ cnt, int* __restrict__ cursor) {
    int bid = blockIdx.x, t = threadIdx.x;
    if (bid < 632) {
        int gid = bid * 256 + t;
        int n = gid >> 4, k0 = (gid & 15) * 8;
        float v[8];
        if (n < N_NODES) {
            #pragma unroll
            for (int u = 0; u < 8; u++) v[u] = x[n * DIN + k0 + u];
        } else {
            #pragma unroll
            for (int u = 0; u < 8; u++) v[u] = 0.f;
        }
        us8 hi, lo;
        #pragma unroll
        for (int u = 0; u < 8; u++) {
            ushort_t h = f2bf(v[u]);
            hi[u] = h;
            lo[u] = f2bf(v[u] - bf2f(h));
        }
        int rb = n >> 7, r = n & 127;
        *(us8*)(Ax + swz_idx(rb, r, k0, 4)) = hi;
        *(us8*)(Ax + swz_idx(rb, r, 128 + k0, 4)) = lo;
    } else if (bid < 888) {
        int i = (bid - 632) * 256 + t;
        int n = i >> 7, k = i & 127;
        ushort_t h = f2bf(ftW[k * DW + n]);
        int cb = n >> 7, rc = n & 127;
        Bx[swz_idx(cb, rc, k, 4)] = h;
        Bx[swz_idx(cb, rc, 128 + k, 4)] = h;
    } else if (bid < 1912) {
        int i = (bid - 888) * 256 + t;
        int n = i >> 9, k = i & 511;
        ushort_t h = f2bf(W1f[k * DW + n]);
        int cb = n >> 7, rc = n & 127;
        B1[swz_idx(cb, rc, k, 16)] = h;
        B1[swz_idx(cb, rc, 512 + k, 16)] = h;
    } else {
        int i = (bid - 1912) * 256 + t;
        if (i < N_NODES) { cnt[i] = 0; cursor[i] = 0; }
    }
}

template<int KT, bool ATT, int EXTRA>
__global__ __launch_bounds__(512, 4) void k_tgemm(const ushort_t* __restrict__ A,
                                                  const ushort_t* __restrict__ Bm,
                                                  float* __restrict__ C,
                                                  ushort_t* __restrict__ Cb,
                                                  const float* __restrict__ asrc,
                                                  const float* __restrict__ adst,
                                                  float* __restrict__ aS,
                                                  float* __restrict__ aD,
                                                  const int* __restrict__ ei,
                                                  int* __restrict__ cnt,
                                                  const int* __restrict__ off,
                                                  int* __restrict__ cursor,
                                                  int* __restrict__ csrc) {
    __shared__ __align__(16) SMem sm;
    int bid = blockIdx.x;
    if (bid >= GEMM_BLKS) {
        int e = (bid - GEMM_BLKS) * 512 + threadIdx.x;
        if (e < N_EDGES) {
            if (EXTRA == 1) {
                atomicAdd(&cnt[ei[N_EDGES + e]], 1);
            } else {
                int d = ei[N_EDGES + e];
                int p = off[d] + atomicAdd(&cursor[d], 1);
                csrc[p] = ei[e];
            }
        }
        return;
    }
    gemm_phase<KT, ATT>(sm, A, Bm, C, Cb, asrc, adst, aS, aD, bid, (int)threadIdx.x);
}

__global__ __launch_bounds__(256) void k_ln_scan(const float* __restrict__ hpre,
                                                 const float* __restrict__ fb,
                                                 const float* __restrict__ g,
                                                 const float* __restrict__ beta,
                                                 ushort_t* __restrict__ h0big,
                                                 const int* __restrict__ cnt,
                                                 int* __restrict__ off) {
    __shared__ int ps[256];
    __shared__ float red[8];
    __shared__ __align__(16) ushort_t st[1024];
    int bid = blockIdx.x, t = threadIdx.x;
    if (bid == MPAD) {
        int base = t * 40;
        int loc[40];
        int s = 0;
        #pragma unroll
        for (int i = 0; i < 40; i++) {
            int idx = base + i;
            int v = idx < N_NODES ? cnt[idx] : 0;
            loc[i] = s; s += v;
        }
        ps[t] = s; __syncthreads();
        for (int o = 1; o < 256; o <<= 1) {
            int v = (t >= o) ? ps[t - o] : 0;
            __syncthreads();
            ps[t] += v;
            __syncthreads();
        }
        int pre = (t > 0) ? ps[t - 1] : 0;
        #pragma unroll
        for (int i = 0; i < 40; i++) {
            int idx = base + i;
            if (idx < N_NODES) off[idx] = pre + loc[i];
        }
        if (t == 255) off[N_NODES] = ps[255];
        return;
    }
    int n = bid;
    int rb = n >> 7, r = n & 127;
    if (n >= N_NODES) {
        if (t < 128) {
            int kp0 = t * 8;
            *(us8*)(h0big + swz_idx(rb, r, kp0, 16)) = (us8){0,0,0,0,0,0,0,0};
        }
        return;
    }
    float a0 = hpre[(size_t)n * DW + t] + fb[t];
    float a1 = hpre[(size_t)n * DW + t + 256] + fb[t + 256];
    float s = a0 + a1, sq = a0 * a0 + a1 * a1;
    for (int o = 32; o > 0; o >>= 1) { s += __shfl_down(s, o, 64); sq += __shfl_down(sq, o, 64); }
    int wid = t >> 6;
    if ((t & 63) == 0) { red[wid] = s; red[4 + wid] = sq; }
    __syncthreads();
    if (t == 0) {
        float ts = red[0] + red[1] + red[2] + red[3];
        float tq = red[4] + red[5] + red[6] + red[7];
        float mu = ts / DW;
        float var = tq / DW - mu * mu;
        red[0] = mu; red[1] = rsqrtf(var + 1e-5f);
    }
    __syncthreads();
    float mu = red[0], rs = red[1];
    float v0 = (a0 - mu) * rs * g[t] + beta[t];
    float v1 = (a1 - mu) * rs * g[t + 256] + beta[t + 256];
    v0 = v0 >= 0.f ? v0 : 0.2f * v0;
    v1 = v1 >= 0.f ? v1 : 0.2f * v1;
    ushort_t h0_ = f2bf(v0), l0_ = f2bf(v0 - bf2f(h0_));
    ushort_t h1_ = f2bf(v1), l1_ = f2bf(v1 - bf2f(h1_));
    st[t] = h0_;        st[256 + t] = h1_;
    st[512 + t] = l0_;  st[768 + t] = l1_;
    __syncthreads();
    if (t < 128) {
        int kp0 = t * 8;
        *(us8*)(h0big + swz_idx(rb, r, kp0, 16)) = *(const us8*)(st + kp0);
    }
}

__global__ __launch_bounds__(256) void k_agg1csr(
    const int* __restrict__ csrc, const int* __restrict__ off,
    const ushort_t* __restrict__ h1b,
    const float* __restrict__ aS, const float* __restrict__ aD,
    const float* __restrict__ b1, const float* __restrict__ bnm,
    const float* __restrict__ bnv, const float* __restrict__ bng,
    const float* __restrict__ bnb, ushort_t* __restrict__ h2b)
{
    int n = blockIdx.x, t = threadIdx.x;
    int beg = off[n], end = off[n + 1];
    __shared__ float wls[64][NHEAD];
    __shared__ int   sls[64];
    __shared__ float aDn[NHEAD];
    __shared__ float dsum[NHEAD];
    if (t < NHEAD) { aDn[t] = aD[n * NHEAD + t]; dsum[t] = 0.f; }
    __syncthreads();
    float acc0 = 0.f, acc1 = 0.f, dpart = 0.f;
    int hA = t >> 5;
    for (int c = beg; c < end; c += 64) {
        int m = min(64, end - c);
        if (t < m) sls[t] = csrc[c + t];
        __syncthreads();
        for (int idx = t; idx < m * NHEAD; idx += 256) {
            int el = idx >> 3, h = idx & 7;
            float l = aS[sls[el] * NHEAD + h] + aDn[h];
            l = l >= 0.f ? l : 0.2f * l;
            float w = __expf(l);
            wls[el][h] = w;
            dpart += w;
        }
        __syncthreads();
        for (int el = 0; el < m; el++) {
            float w = wls[el][hA];
            unsigned v = *(const unsigned*)(h1b + (size_t)sls[el] * DW + 2 * t);
            acc0 += w * __builtin_bit_cast(float, v << 16);
            acc1 += w * __builtin_bit_cast(float, v & 0xffff0000u);
        }
        __syncthreads();
    }
    for (int o = 8; o < 64; o <<= 1) dpart += __shfl_down(dpart, o, 64);
    if ((t & 63) < NHEAD) atomicAdd(&dsum[t & 7], dpart);
    __syncthreads();
    float rd = dsum[hA] > 0.f ? 1.f / dsum[hA] : 0.f;
    int j0 = 2 * t, j1 = 2 * t + 1;
    float v0 = acc0 * rd + b1[j0];
    v0 = (v0 - bnm[j0]) * rsqrtf(bnv[j0] + 1e-5f) * bng[j0] + bnb[j0];
    v0 = v0 > 0.f ? v0 : 0.f;
    float v1 = acc1 * rd + b1[j1];
    v1 = (v1 - bnm[j1]) * rsqrtf(bnv[j1] + 1e-5f) * bng[j1] + bnb[j1];
    v1 = v1 > 0.f ? v1 : 0.f;
    unsigned pk = (unsigned)f2bf(v0) | ((unsigned)f2bf(v1) << 16);
    *(unsigned*)(h2b + (size_t)n * DW + 2 * t) = pk;
}

__global__ __launch_bounds__(256) void k_gemm2att(const ushort_t* __restrict__ h2b,
                                                  const float* __restrict__ W2,
                                                  const float* __restrict__ as2,
                                                  const float* __restrict__ ad2,
                                                  float* __restrict__ gout,
                                                  float* __restrict__ aS,
                                                  float* __restrict__ aD) {
    __shared__ float Ws[DW * 16];
    __shared__ float gl[16][16];
    __shared__ float a2[32];
    int t = threadIdx.x;
    for (int i = t; i < DW * 16; i += 256) Ws[i] = W2[i];
    if (t < 16) a2[t] = as2[t];
    else if (t < 32) a2[t] = ad2[t - 16];
    __syncthreads();
    int nb = blockIdx.x * 16;
    int nl = t >> 4, j = t & 15;
    const bf16x8* hr = (const bf16x8*)(h2b + (size_t)(nb + nl) * DW);
    float acc = 0.f;
    for (int ks = 0; ks < DW / 8; ks++) {
        bf16x8 v = hr[ks];
        #pragma unroll
        for (int u = 0; u < 8; u++)
            acc += bf2f((ushort_t)v[u]) * Ws[(ks * 8 + u) * 16 + j];
    }
    gout[(nb + nl) * 16 + j] = acc;
    gl[nl][j] = acc;
    __syncthreads();
    if (j < 8) {
        aS[(nb + nl) * NHEAD + j] = gl[nl][2 * j] * a2[2 * j] + gl[nl][2 * j + 1] * a2[2 * j + 1];
    } else {
        int h = j - 8;
        aD[(nb + nl) * NHEAD + h] = gl[nl][2 * h] * a2[16 + 2 * h] + gl[nl][2 * h + 1] * a2[16 + 2 * h + 1];
    }
}

__global__ __launch_bounds__(256) void k_agg2csr(
    const int* __restrict__ csrc, const int* __restrict__ off,
    const float* __restrict__ gbuf,
    const float* __restrict__ aS, const float* __restrict__ aD,
    const float* __restrict__ b2, float* __restrict__ outp)
{
    int t = threadIdx.x;
    int n = blockIdx.x * 4 + (t >> 6);
    int lane = t & 63;
    if (n >= N_NODES) return;
    int beg = off[n], end = off[n + 1];
    int j = lane & 15, slot = lane >> 4, h = j >> 1;
    float adn = aD[n * NHEAD + h];
    float acc = 0.f, den = 0.f;
    for (int c = beg + slot; c < end; c += 4) {
        int s = csrc[c];
        float l = aS[s * NHEAD + h] + adn;
        l = l >= 0.f ? l : 0.2f * l;
        float w = __expf(l);
        den += w;
        acc += w * gbuf[s * 16 + j];
    }
    acc += __shfl_down(acc, 16, 64); acc += __shfl_down(acc, 32, 64);
    den += __shfl_down(den, 16, 64); den += __shfl_down(den, 32, 64);
    float v = (lane < 16 && den > 0.f) ? acc / den : 0.f;
    v += __shfl_down(v, 2, 64);
    v += __shfl_down(v, 4, 64);
    v += __shfl_down(v, 8, 64);
    if (lane < 2) outp[n * 2 + lane] = v * 0.125f + b2[lane];
}

extern "C" void kernel_launch(void* const* d_in, const int* in_sizes, int n_in,
                              void* d_out, int out_size, void* d_ws, size_t ws_size,
                              hipStream_t stream) {
    const float* x    = (const float*)d_in[0];
    const int*   ei   = (const int*)d_in[1];
    const float* ftW  = (const float*)d_in[2];
    const float* ftb  = (const float*)d_in[3];
    const float* lng  = (const float*)d_in[4];
    const float* lnb  = (const float*)d_in[5];
    const float* W1   = (const float*)d_in[6];
    const float* as1  = (const float*)d_in[7];
    const float* ad1  = (const float*)d_in[8];
    const float* b1   = (const float*)d_in[9];
    const float* bng  = (const float*)d_in[10];
    const float* bnb  = (const float*)d_in[11];
    const float* bnm  = (const float*)d_in[12];
    const float* bnv  = (const float*)d_in[13];
    const float* W2   = (const float*)d_in[14];
    const float* as2  = (const float*)d_in[15];
    const float* ad2  = (const float*)d_in[16];
    const float* b2   = (const float*)d_in[17];
    float* out = (float*)d_out;

    float* F = (float*)d_ws;
    ushort_t* Ax    = (ushort_t*)(F + 0);
    float*    gbuf  = F + 0;
    ushort_t* Bx    = (ushort_t*)(F + 1294336);
    ushort_t* B1    = (ushort_t*)(F + 1359872);
    float*    hpre  = F + 1622016;
    ushort_t* h2b   = (ushort_t*)(F + 1622016);
    ushort_t* h0big = (ushort_t*)(F + 6799360);
    ushort_t* h1b   = (ushort_t*)(F + 11976704);
    float*    aS1   = F + 14536704;
    float*    aD1   = F + 14616704;
    int* cnt        = (int*)(F + 14696704);
    int* cursor     = (int*)(F + 14706704);
    int* off        = (int*)(F + 14716704);
    int* csrc       = (int*)(F + 14726705);

    MegaArgs ha;
    ha.x = x; ha.ftW = ftW; ha.ftb = ftb; ha.lng = lng; ha.lnb = lnb;
    ha.W1 = W1; ha.as1 = as1; ha.ad1 = ad1; ha.b1 = b1;
    ha.bng = bng; ha.bnb = bnb; ha.bnm = bnm; ha.bnv = bnv;
    ha.W2 = W2; ha.as2 = as2; ha.ad2 = ad2; ha.b2 = b2;
    ha.ei = ei; ha.out = out;
    ha.Ax = Ax; ha.Bx = Bx; ha.B1 = B1; ha.h0big = h0big; ha.h1b = h1b; ha.h2b = h2b;
    ha.hpre = hpre; ha.gbuf = gbuf; ha.aS = aS1; ha.aD = aD1;
    ha.cnt = cnt; ha.cursor = cursor; ha.off = off; ha.csrc = csrc;

    void* kp[] = { (void*)&ha };
    hipError_t err = hipLaunchCooperativeKernel((const void*)k_mega, dim3(NBLK),
                                                dim3(NTHR), kp, 0, stream);
    if (err != hipSuccess) {
        // fallback: round-8 7-kernel path
        k_prep<<<1952, 256, 0, stream>>>(x, ftW, W1, Ax, Bx, B1, cnt, cursor);
        k_tgemm<4, false, 1><<<GEMM_BLKS + 313, 512, 0, stream>>>(
            Ax, Bx, hpre, nullptr, nullptr, nullptr, nullptr, nullptr,
            ei, cnt, nullptr, nullptr, nullptr);
        k_ln_scan<<<MPAD + 1, 256, 0, stream>>>(hpre, ftb, lng, lnb, h0big, cnt, off);
        k_tgemm<16, true, 2><<<GEMM_BLKS + 313, 512, 0, stream>>>(
            h0big, B1, nullptr, h1b, as1, ad1, aS1, aD1,
            ei, nullptr, off, cursor, csrc);
        k_agg1csr<<<N_NODES, 256, 0, stream>>>(csrc, off, h1b, aS1, aD1, b1, bnm, bnv, bng, bnb, h2b);
        k_gemm2att<<<N_NODES / 16, 256, 0, stream>>>(h2b, W2, as2, ad2, gbuf, aS1, aD1);
        k_agg2csr<<<(N_NODES + 3) / 4, 256, 0, stream>>>(csrc, off, gbuf, aS1, aD1, b2, out);
    }
}

// Round 10
// 120.530 us; speedup vs baseline: 4.6230x; 4.6230x over previous
//
#include <hip/hip_runtime.h>
#include <hip/hip_bf16.h>
#include <math.h>

#define N_NODES 10000
#define N_EDGES 160000
#define DIN 128
#define DW 512
#define NHEAD 8
#define NC 64
#define MPAD 10112     // 79 * 128
#define GEMM_BLKS 316  // 79 * 4

typedef unsigned short ushort_t;
typedef __attribute__((ext_vector_type(8))) short bf16x8;
typedef __attribute__((ext_vector_type(8))) unsigned short us8;
typedef __attribute__((ext_vector_type(4))) float f32x4;

__device__ inline ushort_t f2bf(float v) {
    unsigned u = __builtin_bit_cast(unsigned, v);
    return (ushort_t)((u + 0x7fff + ((u >> 16) & 1)) >> 16);
}
__device__ inline float bf2f(ushort_t h) {
    return __builtin_bit_cast(float, (unsigned)h << 16);
}

// swizzled tile-major index: tiles of 128 rows x 64 k, 8192 ushort each.
__device__ __forceinline__ size_t swz_idx(int rb, int r, int kp, int nkt) {
    int kt = kp >> 6, kc = kp & 63;
    return ((size_t)(rb * nkt + kt)) * 8192 + r * 64 + (kc ^ ((r & 7) << 3));
}

__device__ __forceinline__ void gld16(const ushort_t* g, ushort_t* l) {
    __builtin_amdgcn_global_load_lds(
        (const __attribute__((address_space(1))) void*)g,
        (__attribute__((address_space(3))) void*)l, 16, 0, 0);
}

// ================= merged prep: prepx(vec) + prepWft + prepW1 + zero =================
__global__ void k_prep(const float* __restrict__ x, const float* __restrict__ ftW,
                       const float* __restrict__ W1f,
                       ushort_t* __restrict__ Ax, ushort_t* __restrict__ Bx,
                       ushort_t* __restrict__ B1,
                       int* __restrict__ cnt, int* __restrict__ cursor) {
    int bid = blockIdx.x, t = threadIdx.x;
    if (bid < 632) {                        // prepx: Ax[MPAD][256] = [xhi | xlo], 16B stores
        int gid = bid * 256 + t;            // n * 16 + chunk
        int n = gid >> 4, k0 = (gid & 15) * 8;
        float v[8];
        if (n < N_NODES) {
            #pragma unroll
            for (int u = 0; u < 8; u++) v[u] = x[n * DIN + k0 + u];
        } else {
            #pragma unroll
            for (int u = 0; u < 8; u++) v[u] = 0.f;
        }
        us8 hi, lo;
        #pragma unroll
        for (int u = 0; u < 8; u++) {
            ushort_t h = f2bf(v[u]);
            hi[u] = h;
            lo[u] = f2bf(v[u] - bf2f(h));
        }
        int rb = n >> 7, r = n & 127;
        *(us8*)(Ax + swz_idx(rb, r, k0, 4)) = hi;
        *(us8*)(Ax + swz_idx(rb, r, 128 + k0, 4)) = lo;
    } else if (bid < 888) {                 // prepWft: Bx[512][256] = [Whi | Whi]
        int i = (bid - 632) * 256 + t;
        int n = i >> 7, k = i & 127;
        ushort_t h = f2bf(ftW[k * DW + n]);
        int cb = n >> 7, rc = n & 127;
        Bx[swz_idx(cb, rc, k, 4)] = h;
        Bx[swz_idx(cb, rc, 128 + k, 4)] = h;
    } else if (bid < 1912) {                // prepW1: B1[512][1024] = [W1hi | W1hi]
        int i = (bid - 888) * 256 + t;
        int n = i >> 9, k = i & 511;
        ushort_t h = f2bf(W1f[k * DW + n]);
        int cb = n >> 7, rc = n & 127;
        B1[swz_idx(cb, rc, k, 16)] = h;
        B1[swz_idx(cb, rc, 512 + k, 16)] = h;
    } else {                                // zero cnt/cursor
        int i = (bid - 1912) * 256 + t;
        if (i < N_NODES) { cnt[i] = 0; cursor[i] = 0; }
    }
}

// ================= LDS-DMA double-buffered bf16 MFMA GEMM, 8 waves (+side work) =================
// C = A[MPAD][KT*64] @ B[512][KT*64]^T ; pre-swizzled tile-major operands.
// 128x128 tile, 512 threads: wave = 32 rows x 64 cols (acc[2][4]).
// EXTRA: 1 = CSR count, 2 = CSR scatter (blocks >= GEMM_BLKS).
template<int KT, bool ATT, int EXTRA>
__global__ __launch_bounds__(512, 4) void k_tgemm(const ushort_t* __restrict__ A,
                                                  const ushort_t* __restrict__ Bm,
                                                  float* __restrict__ C,
                                                  ushort_t* __restrict__ Cb,
                                                  const float* __restrict__ asrc,
                                                  const float* __restrict__ adst,
                                                  float* __restrict__ aS,
                                                  float* __restrict__ aD,
                                                  const int* __restrict__ ei,
                                                  int* __restrict__ cnt,
                                                  const int* __restrict__ off,
                                                  int* __restrict__ cursor,
                                                  int* __restrict__ csrc) {
    __shared__ __align__(16) ushort_t As[2][8192];
    __shared__ __align__(16) ushort_t Bs[2][8192];
    int bid = blockIdx.x;
    if (bid >= GEMM_BLKS) {                 // ---- CSR side work ----
        int e = (bid - GEMM_BLKS) * 512 + threadIdx.x;
        if (e < N_EDGES) {
            if (EXTRA == 1) {
                atomicAdd(&cnt[ei[N_EDGES + e]], 1);
            } else {
                int d = ei[N_EDGES + e];
                int p = off[d] + atomicAdd(&cursor[d], 1);
                csrc[p] = ei[e];
            }
        }
        return;
    }
    int bx = bid >> 2, by = bid & 3;
    int t = threadIdx.x, w = t >> 6, l = t & 63;
    int lm = l & 15, g = l >> 4;
    int wr = w >> 1, wc = w & 1;            // 4 row-stripes x 2 col-stripes
    int rowbase = bx * 128;
    int colbase = by * 128;

    const ushort_t* Abase = A + (size_t)bx * KT * 8192 + t * 8;
    const ushort_t* Bbase = Bm + (size_t)by * KT * 8192 + t * 8;

    f32x4 acc[2][4];
    #pragma unroll
    for (int r = 0; r < 2; r++)
        #pragma unroll
        for (int c = 0; c < 4; c++) acc[r][c] = (f32x4){0.f, 0.f, 0.f, 0.f};

    {   // prologue: tile 0 -> buf 0 (4 DMA/thread)
        #pragma unroll
        for (int j = 0; j < 2; ++j) {
            gld16(Abase + j * 4096, &As[0][j * 4096 + t * 8]);
            gld16(Bbase + j * 4096, &Bs[0][j * 4096 + t * 8]);
        }
    }

    int p = 0;
    for (int kt = 0; kt < KT; ++kt) {
        __builtin_amdgcn_s_barrier();       // all waves done reading buf[p^1]
        if (kt + 1 < KT) {
            const ushort_t* ga = Abase + (size_t)(kt + 1) * 8192;
            const ushort_t* gb = Bbase + (size_t)(kt + 1) * 8192;
            #pragma unroll
            for (int j = 0; j < 2; ++j) {
                gld16(ga + j * 4096, &As[p ^ 1][j * 4096 + t * 8]);
                gld16(gb + j * 4096, &Bs[p ^ 1][j * 4096 + t * 8]);
            }
            asm volatile("s_waitcnt vmcnt(4)" ::: "memory");   // tile kt landed
        } else {
            asm volatile("s_waitcnt vmcnt(0)" ::: "memory");
        }
        __builtin_amdgcn_s_barrier();       // ALL waves' tile-kt DMA complete
        const char* Ap = (const char*)As[p];
        const char* Bp = (const char*)Bs[p];
        #pragma unroll
        for (int ks = 0; ks < 2; ++ks) {
            bf16x8 af[2], bfr[4];
            #pragma unroll
            for (int r = 0; r < 2; ++r) {
                int row = wr * 32 + r * 16 + lm;
                af[r] = *(const bf16x8*)(Ap + row * 128 +
                                         ((ks * 64 + g * 16) ^ ((row & 7) << 4)));
            }
            #pragma unroll
            for (int c = 0; c < 4; ++c) {
                int col = wc * 64 + c * 16 + lm;
                bfr[c] = *(const bf16x8*)(Bp + col * 128 +
                                          ((ks * 64 + g * 16) ^ ((col & 7) << 4)));
            }
            #pragma unroll
            for (int r = 0; r < 2; ++r)
                #pragma unroll
                for (int c = 0; c < 4; ++c)
                    acc[r][c] = __builtin_amdgcn_mfma_f32_16x16x32_bf16(af[r], bfr[c], acc[r][c], 0, 0, 0);
        }
        p ^= 1;
    }

    // C/D map: col = lane&15, row = (lane>>4)*4 + q
    if (!ATT) {
        #pragma unroll
        for (int r = 0; r < 2; ++r) {
            int row0 = rowbase + wr * 32 + r * 16 + g * 4;
            #pragma unroll
            for (int c = 0; c < 4; ++c) {
                int col = colbase + wc * 64 + c * 16 + lm;
                #pragma unroll
                for (int q = 0; q < 4; ++q)
                    if (row0 + q < N_NODES) C[(size_t)(row0 + q) * DW + col] = acc[r][c][q];
            }
        }
    } else {
        int h = 2 * by + wc;                  // this wave's head
        float asv[4], adv[4];
        #pragma unroll
        for (int c = 0; c < 4; ++c) {
            asv[c] = asrc[h * NC + c * 16 + lm];
            adv[c] = adst[h * NC + c * 16 + lm];
        }
        #pragma unroll
        for (int r = 0; r < 2; ++r) {
            int row0 = rowbase + wr * 32 + r * 16 + g * 4;
            #pragma unroll
            for (int c = 0; c < 4; ++c) {
                int col = colbase + wc * 64 + c * 16 + lm;
                #pragma unroll
                for (int q = 0; q < 4; ++q)
                    if (row0 + q < N_NODES) Cb[(size_t)(row0 + q) * DW + col] = f2bf(acc[r][c][q]);
            }
            #pragma unroll
            for (int q = 0; q < 4; ++q) {
                float ss = acc[r][0][q] * asv[0] + acc[r][1][q] * asv[1] +
                           acc[r][2][q] * asv[2] + acc[r][3][q] * asv[3];
                float dd = acc[r][0][q] * adv[0] + acc[r][1][q] * adv[1] +
                           acc[r][2][q] * adv[2] + acc[r][3][q] * adv[3];
                #pragma unroll
                for (int m = 1; m < 16; m <<= 1) {
                    ss += __shfl_xor(ss, m, 64);
                    dd += __shfl_xor(dd, m, 64);
                }
                int row = row0 + q;
                if (lm == 0 && row < N_NODES) {
                    aS[row * NHEAD + h] = ss;
                    aD[row * NHEAD + h] = dd;
                }
            }
        }
    }
}

// ================= LN epilogue -> h0big[*][1024] = [hi | lo], vectorized (+ scan block) =================
__global__ __launch_bounds__(256) void k_ln_scan(const float* __restrict__ hpre,
                                                 const float* __restrict__ fb,
                                                 const float* __restrict__ g,
                                                 const float* __restrict__ beta,
                                                 ushort_t* __restrict__ h0big,
                                                 const int* __restrict__ cnt,
                                                 int* __restrict__ off) {
    __shared__ int ps[256];
    __shared__ float red[8];
    __shared__ __align__(16) ushort_t st[1024];
    int bid = blockIdx.x, t = threadIdx.x;
    if (bid == MPAD) {                       // ---- exclusive scan over cnt ----
        int base = t * 40;
        int loc[40];
        int s = 0;
        #pragma unroll
        for (int i = 0; i < 40; i++) {
            int idx = base + i;
            int v = idx < N_NODES ? cnt[idx] : 0;
            loc[i] = s; s += v;
        }
        ps[t] = s; __syncthreads();
        for (int o = 1; o < 256; o <<= 1) {
            int v = (t >= o) ? ps[t - o] : 0;
            __syncthreads();
            ps[t] += v;
            __syncthreads();
        }
        int pre = (t > 0) ? ps[t - 1] : 0;
        #pragma unroll
        for (int i = 0; i < 40; i++) {
            int idx = base + i;
            if (idx < N_NODES) off[idx] = pre + loc[i];
        }
        if (t == 255) off[N_NODES] = ps[255];
        return;
    }
    int n = bid;
    int rb = n >> 7, r = n & 127;
    if (n >= N_NODES) {
        if (t < 128) {
            int kp0 = t * 8;
            *(us8*)(h0big + swz_idx(rb, r, kp0, 16)) = (us8){0,0,0,0,0,0,0,0};
        }
        return;
    }
    float a0 = hpre[(size_t)n * DW + t] + fb[t];
    float a1 = hpre[(size_t)n * DW + t + 256] + fb[t + 256];
    float s = a0 + a1, sq = a0 * a0 + a1 * a1;
    for (int o = 32; o > 0; o >>= 1) { s += __shfl_down(s, o, 64); sq += __shfl_down(sq, o, 64); }
    int wid = t >> 6;
    if ((t & 63) == 0) { red[wid] = s; red[4 + wid] = sq; }
    __syncthreads();
    if (t == 0) {
        float ts = red[0] + red[1] + red[2] + red[3];
        float tq = red[4] + red[5] + red[6] + red[7];
        float mu = ts / DW;
        float var = tq / DW - mu * mu;
        red[0] = mu; red[1] = rsqrtf(var + 1e-5f);
    }
    __syncthreads();
    float mu = red[0], rs = red[1];
    float v0 = (a0 - mu) * rs * g[t] + beta[t];
    float v1 = (a1 - mu) * rs * g[t + 256] + beta[t + 256];
    v0 = v0 >= 0.f ? v0 : 0.2f * v0;
    v1 = v1 >= 0.f ? v1 : 0.2f * v1;
    ushort_t h0_ = f2bf(v0), l0_ = f2bf(v0 - bf2f(h0_));
    ushort_t h1_ = f2bf(v1), l1_ = f2bf(v1 - bf2f(h1_));
    st[t] = h0_;        st[256 + t] = h1_;      // hi occupies kp 0..511
    st[512 + t] = l0_;  st[768 + t] = l1_;      // lo occupies kp 512..1023
    __syncthreads();
    if (t < 128) {
        int kp0 = t * 8;
        *(us8*)(h0big + swz_idx(rb, r, kp0, 16)) = *(const us8*)(st + kp0);
    }
}

// ================= layer-1 aggregation + BN/ReLU + GEMM2 + att2 (fused) =================
// Block n: softmax-weighted gather of h1 rows -> h2 row (LDS, f32) -> g = h2 @ W2 -> aS2/aD2.
__global__ __launch_bounds__(256) void k_agg1g2(
    const int* __restrict__ csrc, const int* __restrict__ off,
    const ushort_t* __restrict__ h1b,
    const float* __restrict__ aS, const float* __restrict__ aD,
    const float* __restrict__ b1, const float* __restrict__ bnm,
    const float* __restrict__ bnv, const float* __restrict__ bng,
    const float* __restrict__ bnb,
    const float* __restrict__ W2, const float* __restrict__ as2,
    const float* __restrict__ ad2,
    float* __restrict__ gbuf, float* __restrict__ aS2, float* __restrict__ aD2)
{
    int n = blockIdx.x, t = threadIdx.x;
    int beg = off[n], end = off[n + 1];
    __shared__ float wls[64][NHEAD];
    __shared__ int   sls[64];
    __shared__ float aDn[NHEAD];
    __shared__ float dsum[NHEAD];
    __shared__ float h2row[DW];
    __shared__ float pr[16][17];
    __shared__ float gl[16];
    if (t < NHEAD) { aDn[t] = aD[n * NHEAD + t]; dsum[t] = 0.f; }
    __syncthreads();
    float acc0 = 0.f, acc1 = 0.f, dpart = 0.f;
    int hA = t >> 5;                       // head of cols 2t, 2t+1
    for (int c = beg; c < end; c += 64) {
        int m = min(64, end - c);
        if (t < m) sls[t] = csrc[c + t];
        __syncthreads();
        for (int idx = t; idx < m * NHEAD; idx += 256) {
            int el = idx >> 3, h = idx & 7;
            float l = aS[sls[el] * NHEAD + h] + aDn[h];
            l = l >= 0.f ? l : 0.2f * l;
            float w = __expf(l);
            wls[el][h] = w;
            dpart += w;
        }
        __syncthreads();
        for (int el = 0; el < m; el++) {
            float w = wls[el][hA];
            unsigned v = *(const unsigned*)(h1b + (size_t)sls[el] * DW + 2 * t);
            acc0 += w * __builtin_bit_cast(float, v << 16);
            acc1 += w * __builtin_bit_cast(float, v & 0xffff0000u);
        }
        __syncthreads();
    }
    for (int o = 8; o < 64; o <<= 1) dpart += __shfl_down(dpart, o, 64);
    if ((t & 63) < NHEAD) atomicAdd(&dsum[t & 7], dpart);
    __syncthreads();
    float rd = dsum[hA] > 0.f ? 1.f / dsum[hA] : 0.f;
    int j0 = 2 * t, j1 = 2 * t + 1;
    float v0 = acc0 * rd + b1[j0];
    v0 = (v0 - bnm[j0]) * rsqrtf(bnv[j0] + 1e-5f) * bng[j0] + bnb[j0];
    v0 = v0 > 0.f ? v0 : 0.f;
    float v1 = acc1 * rd + b1[j1];
    v1 = (v1 - bnm[j1]) * rsqrtf(bnv[j1] + 1e-5f) * bng[j1] + bnb[j1];
    v1 = v1 > 0.f ? v1 : 0.f;
    h2row[j0] = v0;
    h2row[j1] = v1;
    __syncthreads();
    // ---- GEMM2: g[j] = sum_k h2row[k] * W2[k][j], 16 segs x 16 cols ----
    int j = t & 15, seg = t >> 4;
    const float* wp = W2 + (seg * 32) * 16 + j;
    float part = 0.f;
    #pragma unroll 8
    for (int k = 0; k < 32; k++) part += h2row[seg * 32 + k] * wp[k * 16];
    pr[seg][j] = part;
    __syncthreads();
    if (t < 16) {
        float accg = 0.f;
        #pragma unroll
        for (int s2 = 0; s2 < 16; s2++) accg += pr[s2][t];
        gl[t] = accg;
        gbuf[n * 16 + t] = accg;
    }
    __syncthreads();
    if (t < 8) {
        aS2[n * NHEAD + t] = gl[2 * t] * as2[2 * t] + gl[2 * t + 1] * as2[2 * t + 1];
    } else if (t < 16) {
        int h = t - 8;
        aD2[n * NHEAD + h] = gl[2 * h] * ad2[2 * h] + gl[2 * h + 1] * ad2[2 * h + 1];
    }
}

// ================= layer-2 aggregation, CSR, fused head-mean + b2 =================
__global__ __launch_bounds__(256) void k_agg2csr(
    const int* __restrict__ csrc, const int* __restrict__ off,
    const float* __restrict__ gbuf,
    const float* __restrict__ aS, const float* __restrict__ aD,
    const float* __restrict__ b2, float* __restrict__ outp)
{
    int t = threadIdx.x;
    int n = blockIdx.x * 4 + (t >> 6);
    int lane = t & 63;
    if (n >= N_NODES) return;
    int beg = off[n], end = off[n + 1];
    int j = lane & 15, slot = lane >> 4, h = j >> 1;
    float adn = aD[n * NHEAD + h];
    float acc = 0.f, den = 0.f;
    for (int c = beg + slot; c < end; c += 4) {
        int s = csrc[c];
        float l = aS[s * NHEAD + h] + adn;
        l = l >= 0.f ? l : 0.2f * l;
        float w = __expf(l);
        den += w;
        acc += w * gbuf[s * 16 + j];
    }
    acc += __shfl_down(acc, 16, 64); acc += __shfl_down(acc, 32, 64);
    den += __shfl_down(den, 16, 64); den += __shfl_down(den, 32, 64);
    float v = (lane < 16 && den > 0.f) ? acc / den : 0.f;
    v += __shfl_down(v, 2, 64);
    v += __shfl_down(v, 4, 64);
    v += __shfl_down(v, 8, 64);
    if (lane < 2) outp[n * 2 + lane] = v * 0.125f + b2[lane];
}

extern "C" void kernel_launch(void* const* d_in, const int* in_sizes, int n_in,
                              void* d_out, int out_size, void* d_ws, size_t ws_size,
                              hipStream_t stream) {
    const float* x    = (const float*)d_in[0];
    const int*   ei   = (const int*)d_in[1];
    const float* ftW  = (const float*)d_in[2];
    const float* ftb  = (const float*)d_in[3];
    const float* lng  = (const float*)d_in[4];
    const float* lnb  = (const float*)d_in[5];
    const float* W1   = (const float*)d_in[6];
    const float* as1  = (const float*)d_in[7];
    const float* ad1  = (const float*)d_in[8];
    const float* b1   = (const float*)d_in[9];
    const float* bng  = (const float*)d_in[10];
    const float* bnb  = (const float*)d_in[11];
    const float* bnm  = (const float*)d_in[12];
    const float* bnv  = (const float*)d_in[13];
    const float* W2   = (const float*)d_in[14];
    const float* as2  = (const float*)d_in[15];
    const float* ad2  = (const float*)d_in[16];
    const float* b2   = (const float*)d_in[17];
    float* out = (float*)d_out;

    // ---- workspace (float offsets), lifetime-aliased, ~60.2 MB ----
    float* F = (float*)d_ws;
    ushort_t* Ax    = (ushort_t*)(F + 0);          // 1,294,336 f (dead after ft GEMM)
    float*    gbuf  = F + 0;                       // 160,000 f
    ushort_t* Bx    = (ushort_t*)(F + 1294336);    // 65,536 f
    ushort_t* B1    = (ushort_t*)(F + 1359872);    // 262,144 f
    float*    hpre  = F + 1622016;                 // 5,177,344 f (dead after LN)
    ushort_t* h0big = (ushort_t*)(F + 6799360);    // 5,177,344 f
    ushort_t* h1b   = (ushort_t*)(F + 11976704);   // 2,560,000 f
    float*    aS1   = F + 14536704;                // 80,000
    float*    aD1   = F + 14616704;                // 80,000
    float*    aS2   = F + 14696704;                // 80,000
    float*    aD2   = F + 14776704;                // 80,000
    int* cnt        = (int*)(F + 14856704);
    int* cursor     = (int*)(F + 14866704);
    int* off        = (int*)(F + 14876704);
    int* csrc       = (int*)(F + 14886705);        // -> end 15,046,705 f

    // 1. merged prep (Ax-vec + Bx + B1 + zero)
    k_prep<<<1952, 256, 0, stream>>>(x, ftW, W1, Ax, Bx, B1, cnt, cursor);
    // 2. ft GEMM (K'=256) + CSR count
    k_tgemm<4, false, 1><<<GEMM_BLKS + 313, 512, 0, stream>>>(
        Ax, Bx, hpre, nullptr, nullptr, nullptr, nullptr, nullptr,
        ei, cnt, nullptr, nullptr, nullptr);
    // 3. LN -> h0big (K'=1024 [hi|lo], vectorized) + CSR scan
    k_ln_scan<<<MPAD + 1, 256, 0, stream>>>(hpre, ftb, lng, lnb, h0big, cnt, off);
    // 4. GEMM1 (K'=1024) + fused att-dots + CSR scatter
    k_tgemm<16, true, 2><<<GEMM_BLKS + 313, 512, 0, stream>>>(
        h0big, B1, nullptr, h1b, as1, ad1, aS1, aD1,
        ei, nullptr, off, cursor, csrc);
    // 5. agg1 + BN/ReLU + GEMM2 + att2 (fused)
    k_agg1g2<<<N_NODES, 256, 0, stream>>>(csrc, off, h1b, aS1, aD1,
                                          b1, bnm, bnv, bng, bnb,
                                          W2, as2, ad2, gbuf, aS2, aD2);
    // 6. layer-2 aggregation (fused head-mean + b2)
    k_agg2csr<<<(N_NODES + 3) / 4, 256, 0, stream>>>(csrc, off, gbuf, aS2, aD2, b2, out);
}